// Round 1
// baseline (144.323 us; speedup 1.0000x reference)
//
#include <hip/hip_runtime.h>
#include <hip/hip_bf16.h>

// Sizes (fixed by the problem)
//   B=128, M=1024, D_Z=1024, D_PHI=512, H1=512, H2=512
// ws layout: hzb f32[128*512] | hp f32[1024*512] | W2T bf16[512*512]  (~2.88 MB)

typedef __bf16 bf16x8 __attribute__((ext_vector_type(8)));
typedef float  f32x4  __attribute__((ext_vector_type(4)));

// tanh-form GELU: x * (1 - 1/(exp2(2*sqrt(2/pi)*log2e * (x + 0.044715 x^3)) + 1))
// max |dev| from exact erf-GELU ~5e-4 — inside the error budget.
__device__ __forceinline__ float gelu_f(float x) {
    float t = x * x;
    float inner = __builtin_fmaf(0.044715f * t, x, x);
    float e = __builtin_amdgcn_exp2f(2.3022082f * inner);
    float r = __builtin_amdgcn_rcpf(e + 1.0f);
    return __builtin_fmaf(-x, r, x);   // x * (1 - r)
}

__device__ __forceinline__ unsigned int pack_bf16x2(float a, float b) {
    __hip_bfloat162 h = __float22bfloat162_rn(make_float2(a, b));
    return *reinterpret_cast<unsigned int*>(&h);
}

// ---------------- stage 1: hzb / hp (fp32) + W2 transpose->bf16 ----------------
// grid 640 x 256:
//   blocks [0,64):    hzb tiles, 16 rows x 64 cols, K=1024
//   blocks [64,576):  hp  tiles, 16 rows x 64 cols, K=512
//   blocks [576,640): W2T 64x64 transpose tiles
__global__ __launch_bounds__(256) void prep_kernel(
    const float* __restrict__ g_q, const float* __restrict__ Phi,
    const float* __restrict__ W1, const float* __restrict__ b1,
    const float* __restrict__ W2,
    float* __restrict__ hzb, float* __restrict__ hp,
    unsigned short* __restrict__ W2T)
{
    __shared__ float smem[16 * 1024];   // 64 KB
    const int t = threadIdx.x;
    const int id = blockIdx.x;

    if (id < 64) {
        // ----- hzb = g_q @ W1[:1024] + b1 -----
        const int rt = id >> 3, ct = id & 7;
        const int r0 = rt * 16, c0 = ct * 64;
        #pragma unroll
        for (int i = 0; i < 16; ++i) {             // load g_q tile [16][1024]
            int v = i * 256 + t;
            int r = v >> 8, c4 = v & 255;
            *(float4*)&smem[r * 1024 + c4 * 4] =
                *(const float4*)&g_q[(r0 + r) * 1024 + c4 * 4];
        }
        __syncthreads();
        const int c = c0 + (t & 63);
        const int g = t >> 6;
        float a0 = 0.f, a1 = 0.f, a2 = 0.f, a3 = 0.f;
        for (int j = 0; j < 1024; ++j) {
            float w = W1[j * 512 + c];
            a0 = __builtin_fmaf(smem[(g * 4 + 0) * 1024 + j], w, a0);
            a1 = __builtin_fmaf(smem[(g * 4 + 1) * 1024 + j], w, a1);
            a2 = __builtin_fmaf(smem[(g * 4 + 2) * 1024 + j], w, a2);
            a3 = __builtin_fmaf(smem[(g * 4 + 3) * 1024 + j], w, a3);
        }
        float bb = b1[c];
        hzb[(r0 + g * 4 + 0) * 512 + c] = a0 + bb;
        hzb[(r0 + g * 4 + 1) * 512 + c] = a1 + bb;
        hzb[(r0 + g * 4 + 2) * 512 + c] = a2 + bb;
        hzb[(r0 + g * 4 + 3) * 512 + c] = a3 + bb;
    } else if (id < 576) {
        // ----- hp = Phi @ W1[1024:] -----
        const int id2 = id - 64;
        const int rt = id2 >> 3, ct = id2 & 7;
        const int r0 = rt * 16, c0 = ct * 64;
        #pragma unroll
        for (int i = 0; i < 8; ++i) {              // load Phi tile [16][512]
            int v = i * 256 + t;
            int r = v >> 7, c4 = v & 127;
            *(float4*)&smem[r * 512 + c4 * 4] =
                *(const float4*)&Phi[(r0 + r) * 512 + c4 * 4];
        }
        __syncthreads();
        const int c = c0 + (t & 63);
        const int g = t >> 6;
        float a0 = 0.f, a1 = 0.f, a2 = 0.f, a3 = 0.f;
        for (int j = 0; j < 512; ++j) {
            float w = W1[(1024 + j) * 512 + c];
            a0 = __builtin_fmaf(smem[(g * 4 + 0) * 512 + j], w, a0);
            a1 = __builtin_fmaf(smem[(g * 4 + 1) * 512 + j], w, a1);
            a2 = __builtin_fmaf(smem[(g * 4 + 2) * 512 + j], w, a2);
            a3 = __builtin_fmaf(smem[(g * 4 + 3) * 512 + j], w, a3);
        }
        hp[(r0 + g * 4 + 0) * 512 + c] = a0;
        hp[(r0 + g * 4 + 1) * 512 + c] = a1;
        hp[(r0 + g * 4 + 2) * 512 + c] = a2;
        hp[(r0 + g * 4 + 3) * 512 + c] = a3;
    } else {
        // ----- W2T[n][k] = bf16(W2[k][n]) via 64x64 LDS tile (pad 68 keeps f4 align) -----
        const int id3 = id - 576;
        const int kt = id3 >> 3, nt = id3 & 7;
        const int k0 = kt * 64, n0 = nt * 64;
        float* tr = smem;                          // [64][68]
        {
            int r = t >> 2, c16 = (t & 3) * 16;
            #pragma unroll
            for (int q = 0; q < 4; ++q)
                *(float4*)&tr[r * 68 + c16 + q * 4] =
                    *(const float4*)&W2[(k0 + r) * 512 + n0 + c16 + q * 4];
        }
        __syncthreads();
        int nl = t >> 2, kc = (t & 3) * 16;
        unsigned int pk[8];
        #pragma unroll
        for (int i = 0; i < 8; ++i) {
            float f0 = tr[(kc + 2 * i    ) * 68 + nl];
            float f1 = tr[(kc + 2 * i + 1) * 68 + nl];
            pk[i] = pack_bf16x2(f0, f1);
        }
        unsigned int idx = (unsigned int)(n0 + nl) * 512u + (unsigned int)(k0 + kc);
        *(uint4*)&W2T[idx]     = make_uint4(pk[0], pk[1], pk[2], pk[3]);
        *(uint4*)&W2T[idx + 8] = make_uint4(pk[4], pk[5], pk[6], pk[7]);
    }
}

// ---------------- stage 2: fused  gelu1 -> bf16 GEMM (x W2) -> gelu2 -> dot W3 ----------------
// block: 64 rows (one b, 64 consecutive m) x 512 cols (all H2), 8 waves, wave = 64x64.
// LDS: W2T tile [512 n][64 k] bf16 (64KB, XOR-swizzled 16B chunks) + A tile [64][64] bf16 (8KB).
__global__ __launch_bounds__(512, 2) void fused_kernel(
    const float* __restrict__ hzb, const float* __restrict__ hp,
    const unsigned short* __restrict__ W2T,
    const float* __restrict__ b2, const float* __restrict__ W3,
    const float* __restrict__ b3, float* __restrict__ out)
{
    __shared__ unsigned short lW2[512 * 64];   // 64 KB
    __shared__ unsigned short lA[64 * 64];     // 8 KB
    __shared__ float lhz[512];
    __shared__ float lred[8 * 64];

    const int t  = threadIdx.x;
    const int w  = t >> 6;          // wave 0..7 -> col chunk
    const int l  = t & 63;
    const int r0 = blockIdx.x * 64; // global row base (r = b*1024 + m)
    const int b  = r0 >> 10;
    const int m0 = r0 & 1023;

    lhz[t] = hzb[b * 512 + t];      // hz+b1 for this b (512 threads, 512 elems)

    f32x4 acc[4][4];
    #pragma unroll
    for (int a = 0; a < 4; ++a)
        #pragma unroll
        for (int bf = 0; bf < 4; ++bf)
            acc[a][bf] = f32x4{0.f, 0.f, 0.f, 0.f};

    // A-gen fixed mapping: thread -> (row, k-chunk)
    const int arow = t >> 3;        // 0..63
    const int ac   = t & 7;         // 16B chunk within 128B row
    const unsigned int awoff = (unsigned)(arow * 128 + ((ac ^ (arow & 7)) << 4));
    const float4* hp4 = (const float4*)&hp[(m0 + arow) * 512];

    __syncthreads();

    #pragma unroll 1
    for (int kt = 0; kt < 8; ++kt) {
        const int k0 = kt * 64;

        // --- stage W2T tile: 8x global_load_lds(16B), source pre-swizzled (rule #21) ---
        #pragma unroll
        for (int i = 0; i < 8; ++i) {
            int n  = i * 64 + (t >> 3);
            int sc = (t & 7) ^ (n & 7);
            const unsigned short* src = W2T + (unsigned)(n * 512 + k0 + sc * 8);
            unsigned int dst = (unsigned)(i * 8192 + t * 16);
            __builtin_amdgcn_global_load_lds(
                (const __attribute__((address_space(1))) void*)src,
                (__attribute__((address_space(3))) void*)((char*)lW2 + dst),
                16, 0, 0);
        }

        // --- generate A tile: gelu(hz + hp) -> bf16, swizzled ds_write_b128 ---
        {
            const int kb = k0 + ac * 8;
            float4 p0 = hp4[(kb >> 2)];
            float4 p1 = hp4[(kb >> 2) + 1];
            float g0 = gelu_f(p0.x + lhz[kb + 0]);
            float g1 = gelu_f(p0.y + lhz[kb + 1]);
            float g2 = gelu_f(p0.z + lhz[kb + 2]);
            float g3 = gelu_f(p0.w + lhz[kb + 3]);
            float g4 = gelu_f(p1.x + lhz[kb + 4]);
            float g5 = gelu_f(p1.y + lhz[kb + 5]);
            float g6 = gelu_f(p1.z + lhz[kb + 6]);
            float g7 = gelu_f(p1.w + lhz[kb + 7]);
            uint4 pk;
            pk.x = pack_bf16x2(g0, g1);
            pk.y = pack_bf16x2(g2, g3);
            pk.z = pack_bf16x2(g4, g5);
            pk.w = pack_bf16x2(g6, g7);
            *(uint4*)((char*)lA + awoff) = pk;
        }

        __syncthreads();   // compiler drains vmcnt/lgkmcnt before s_barrier

        // --- compute: per wave 64x64, 2 kk halves x (4 A-frags, 4 B-frags, 16 mfma) ---
        #pragma unroll
        for (int kk = 0; kk < 2; ++kk) {
            const int cbase = 4 * kk + (l >> 4);
            bf16x8 af[4];
            #pragma unroll
            for (int a = 0; a < 4; ++a) {
                int row = 16 * a + (l & 15);
                unsigned off = (unsigned)(row * 128 + ((cbase ^ (row & 7)) << 4));
                af[a] = __builtin_bit_cast(bf16x8, *(const uint4*)((const char*)lA + off));
            }
            #pragma unroll
            for (int bf = 0; bf < 4; ++bf) {
                int n = w * 64 + 16 * bf + (l & 15);
                unsigned off = (unsigned)(n * 128 + ((cbase ^ (n & 7)) << 4));
                bf16x8 bfr = __builtin_bit_cast(bf16x8, *(const uint4*)((const char*)lW2 + off));
                #pragma unroll
                for (int a = 0; a < 4; ++a)
                    acc[a][bf] = __builtin_amdgcn_mfma_f32_16x16x32_bf16(
                        af[a], bfr, acc[a][bf], 0, 0, 0);
            }
        }

        __syncthreads();   // compute done before next stage overwrites LDS
    }

    // --- epilogue: +b2, gelu2, dot W3, reduce ---
    float b2v[4], w3v[4];
    #pragma unroll
    for (int bf = 0; bf < 4; ++bf) {
        int n = w * 64 + 16 * bf + (l & 15);
        b2v[bf] = b2[n];
        w3v[bf] = W3[n];
    }
    float psum[4][4];
    #pragma unroll
    for (int a = 0; a < 4; ++a)
        #pragma unroll
        for (int r = 0; r < 4; ++r) psum[a][r] = 0.f;

    #pragma unroll
    for (int bf = 0; bf < 4; ++bf)
        #pragma unroll
        for (int a = 0; a < 4; ++a)
            #pragma unroll
            for (int r = 0; r < 4; ++r) {
                float x = acc[a][bf][r] + b2v[bf];
                float h = gelu_f(x);
                psum[a][r] = __builtin_fmaf(h, w3v[bf], psum[a][r]);
            }

    #pragma unroll
    for (int a = 0; a < 4; ++a)
        #pragma unroll
        for (int r = 0; r < 4; ++r) {
            float v = psum[a][r];
            v += __shfl_xor(v, 1);
            v += __shfl_xor(v, 2);
            v += __shfl_xor(v, 4);
            v += __shfl_xor(v, 8);
            psum[a][r] = v;
        }

    if ((l & 15) == 0) {
        int gb = (l >> 4) * 4;
        #pragma unroll
        for (int a = 0; a < 4; ++a)
            #pragma unroll
            for (int r = 0; r < 4; ++r)
                lred[w * 64 + 16 * a + gb + r] = psum[a][r];
    }
    __syncthreads();
    if (t < 64) {
        float s = b3[0];
        #pragma unroll
        for (int ww = 0; ww < 8; ++ww) s += lred[ww * 64 + t];
        out[r0 + t] = s;
    }
}

extern "C" void kernel_launch(void* const* d_in, const int* in_sizes, int n_in,
                              void* d_out, int out_size, void* d_ws, size_t ws_size,
                              hipStream_t stream) {
    (void)in_sizes; (void)n_in; (void)out_size; (void)ws_size;
    const float* g_q = (const float*)d_in[0];
    const float* Phi = (const float*)d_in[1];
    const float* W1  = (const float*)d_in[2];
    const float* b1  = (const float*)d_in[3];
    const float* W2  = (const float*)d_in[4];
    const float* b2  = (const float*)d_in[5];
    const float* W3  = (const float*)d_in[6];
    const float* b3  = (const float*)d_in[7];
    float* out = (float*)d_out;

    char* ws = (char*)d_ws;
    float* hzb = (float*)ws;                                   // 256 KB
    float* hp  = (float*)(ws + 262144);                        // 2 MB
    unsigned short* W2T = (unsigned short*)(ws + 262144 + 2097152); // 512 KB

    hipLaunchKernelGGL(prep_kernel, dim3(640), dim3(256), 0, stream,
                       g_q, Phi, W1, b1, W2, hzb, hp, W2T);
    hipLaunchKernelGGL(fused_kernel, dim3(2048), dim3(512), 0, stream,
                       hzb, hp, W2T, b2, W3, b3, out);
}